// Round 1
// baseline (974.273 us; speedup 1.0000x reference)
//
#include <hip/hip_runtime.h>
#include <math.h>

#define N_NODES 100000
#define N_EDGES 3200000
#define N_FEAT  500
#define NF4     125      // N_FEAT / 4
#define N_HID   16
#define N_CLS   7

// Workspace layout in floats (total 4.7M floats = 18.8 MB)
#define OFF_DINV 0           // [100000]  degree -> dinv (in place)
#define OFF_M1   100000      // [100000*16] x @ W1
#define OFF_AGG1 1700000     // [100000*16] scatter accumulator, layer 1
#define OFF_M2   3300000     // [100000*7]  h @ W2
#define OFF_AGG2 4000000     // [100000*7]  scatter accumulator, layer 2
#define WS_FLOATS 4700000

// ---------------------------------------------------------------- zero ws
__global__ void zero_ws(float* __restrict__ ws) {
    int i = blockIdx.x * 256 + threadIdx.x;
    float4* w4 = (float4*)ws;
    if (i < WS_FLOATS / 4) w4[i] = make_float4(0.f, 0.f, 0.f, 0.f);
}

// ---------------------------------------------------------------- degree
__global__ void deg_count(const int* __restrict__ dst, float* __restrict__ deg) {
    int e = blockIdx.x * 256 + threadIdx.x;
    if (e < N_EDGES) atomicAdd(&deg[dst[e]], 1.0f);
}

__global__ void finalize_dinv(float* __restrict__ deg) {
    int n = blockIdx.x * 256 + threadIdx.x;
    if (n < N_NODES) deg[n] = rsqrtf(deg[n] + 1.0f);  // +1 = self loop
}

// ---------------------------------------------------------------- m1 = x @ W1
// One wave per row. Lane l covers float4 chunks {l, l+64} of the 125-chunk row
// (coalesced 1KB global reads). W1 is staged transposed in LDS with 504-dword
// row stride so the per-lane ds_read_b128 pattern is contiguous (conflict-free).
__global__ void gemm1(const float* __restrict__ x, const float* __restrict__ W1,
                      float* __restrict__ m1) {
    __shared__ __align__(16) float Wt[16 * 504];
    for (int i = threadIdx.x; i < N_FEAT * N_HID; i += 256) {
        int k = i >> 4, j = i & 15;
        Wt[j * 504 + k] = W1[i];
    }
    __syncthreads();

    int wave = threadIdx.x >> 6;
    int lane = threadIdx.x & 63;
    int row  = blockIdx.x * 4 + wave;
    if (row >= N_NODES) return;

    const float4* x4 = (const float4*)x;
    float acc[16];
#pragma unroll
    for (int j = 0; j < 16; ++j) acc[j] = 0.f;

#pragma unroll
    for (int it = 0; it < 2; ++it) {
        int m = it * 64 + lane;
        if (m < NF4) {
            float4 xv = x4[(size_t)row * NF4 + m];
#pragma unroll
            for (int j = 0; j < 16; ++j) {
                const float4 wv = *(const float4*)&Wt[j * 504 + 4 * m];
                acc[j] += xv.x * wv.x + xv.y * wv.y + xv.z * wv.z + xv.w * wv.w;
            }
        }
    }
    // 64-lane butterfly reduction (all lanes end with the full sums)
#pragma unroll
    for (int off = 32; off > 0; off >>= 1) {
#pragma unroll
        for (int j = 0; j < 16; ++j) acc[j] += __shfl_xor(acc[j], off, 64);
    }
    if (lane == 0) {
        float4* o = (float4*)&m1[(size_t)row * 16];
        o[0] = make_float4(acc[0],  acc[1],  acc[2],  acc[3]);
        o[1] = make_float4(acc[4],  acc[5],  acc[6],  acc[7]);
        o[2] = make_float4(acc[8],  acc[9],  acc[10], acc[11]);
        o[3] = make_float4(acc[12], acc[13], acc[14], acc[15]);
    }
}

// ---------------------------------------------------------------- scatter layer 1
// Thread per (edge, feature). 16 consecutive lanes share an edge -> the 16
// atomics land in one (or two) 64B lines; m1 row gather is a 64B segment.
__global__ void scatter1(const int* __restrict__ src, const int* __restrict__ dst,
                         const float* __restrict__ dinv, const float* __restrict__ m1,
                         float* __restrict__ agg1) {
    int gt = blockIdx.x * 256 + threadIdx.x;
    int e = gt >> 4, j = gt & 15;
    if (e < N_EDGES) {
        int s = src[e], d = dst[e];
        float nrm = dinv[s] * dinv[d];
        atomicAdd(&agg1[(size_t)d * 16 + j], m1[(size_t)s * 16 + j] * nrm);
    }
}

// ---------------------------------------------------------------- epilogue 1 + h @ W2
__global__ void epi1(const float* __restrict__ agg1, const float* __restrict__ m1,
                     const float* __restrict__ dinv, const float* __restrict__ b1,
                     const float* __restrict__ W2, float* __restrict__ m2) {
    __shared__ float sW2[N_HID * N_CLS];
    __shared__ float sb1[N_HID];
    if (threadIdx.x < N_HID * N_CLS) sW2[threadIdx.x] = W2[threadIdx.x];
    if (threadIdx.x < N_HID) sb1[threadIdx.x] = b1[threadIdx.x];
    __syncthreads();

    int n = blockIdx.x * 256 + threadIdx.x;
    if (n >= N_NODES) return;
    float di = dinv[n];
    float d2 = di * di;
    float h[N_HID];
#pragma unroll
    for (int j = 0; j < N_HID; ++j) {
        float v = agg1[(size_t)n * 16 + j] + m1[(size_t)n * 16 + j] * d2 + sb1[j];
        h[j] = v > 0.f ? v : 0.f;
    }
#pragma unroll
    for (int c = 0; c < N_CLS; ++c) {
        float acc = 0.f;
#pragma unroll
        for (int j = 0; j < N_HID; ++j) acc += h[j] * sW2[j * N_CLS + c];
        m2[(size_t)n * N_CLS + c] = acc;
    }
}

// ---------------------------------------------------------------- scatter layer 2
__global__ void scatter2(const int* __restrict__ src, const int* __restrict__ dst,
                         const float* __restrict__ dinv, const float* __restrict__ m2,
                         float* __restrict__ agg2) {
    int gt = blockIdx.x * 256 + threadIdx.x;
    int e = gt >> 3, j = gt & 7;
    if (e < N_EDGES && j < N_CLS) {
        int s = src[e], d = dst[e];
        float nrm = dinv[s] * dinv[d];
        atomicAdd(&agg2[(size_t)d * N_CLS + j], m2[(size_t)s * N_CLS + j] * nrm);
    }
}

// ---------------------------------------------------------------- epilogue 2 + log_softmax
__global__ void epi2(const float* __restrict__ agg2, const float* __restrict__ m2,
                     const float* __restrict__ dinv, const float* __restrict__ b2,
                     float* __restrict__ out) {
    int n = blockIdx.x * 256 + threadIdx.x;
    if (n >= N_NODES) return;
    float di = dinv[n];
    float d2 = di * di;
    float v[N_CLS];
    float mx = -1e30f;
#pragma unroll
    for (int c = 0; c < N_CLS; ++c) {
        v[c] = agg2[(size_t)n * N_CLS + c] + m2[(size_t)n * N_CLS + c] * d2 + b2[c];
        mx = fmaxf(mx, v[c]);
    }
    float s = 0.f;
#pragma unroll
    for (int c = 0; c < N_CLS; ++c) s += expf(v[c] - mx);
    float ls = mx + logf(s);
#pragma unroll
    for (int c = 0; c < N_CLS; ++c) out[(size_t)n * N_CLS + c] = v[c] - ls;
}

// ----------------------------------------------------------------
extern "C" void kernel_launch(void* const* d_in, const int* in_sizes, int n_in,
                              void* d_out, int out_size, void* d_ws, size_t ws_size,
                              hipStream_t stream) {
    const float* x  = (const float*)d_in[0];
    const int*   ei = (const int*)d_in[1];
    const float* W1 = (const float*)d_in[2];
    const float* b1 = (const float*)d_in[3];
    const float* W2 = (const float*)d_in[4];
    const float* b2 = (const float*)d_in[5];
    float* out = (float*)d_out;
    float* ws  = (float*)d_ws;   // needs 18.8 MB

    const int* src = ei;              // edge_index[0]
    const int* dst = ei + N_EDGES;    // edge_index[1]
    float* dinv = ws + OFF_DINV;
    float* m1   = ws + OFF_M1;
    float* agg1 = ws + OFF_AGG1;
    float* m2   = ws + OFF_M2;
    float* agg2 = ws + OFF_AGG2;

    zero_ws<<<(WS_FLOATS / 4 + 255) / 256, 256, 0, stream>>>(ws);
    deg_count<<<N_EDGES / 256, 256, 0, stream>>>(dst, dinv);
    finalize_dinv<<<(N_NODES + 255) / 256, 256, 0, stream>>>(dinv);
    gemm1<<<(N_NODES + 3) / 4, 256, 0, stream>>>(x, W1, m1);
    scatter1<<<N_EDGES * 16 / 256, 256, 0, stream>>>(src, dst, dinv, m1, agg1);
    epi1<<<(N_NODES + 255) / 256, 256, 0, stream>>>(agg1, m1, dinv, b1, W2, m2);
    scatter2<<<N_EDGES * 8 / 256, 256, 0, stream>>>(src, dst, dinv, m2, agg2);
    epi2<<<(N_NODES + 255) / 256, 256, 0, stream>>>(agg2, m2, dinv, b2, out);
}